// Round 9
// baseline (206.011 us; speedup 1.0000x reference)
//
#include <hip/hip_runtime.h>
#include <stdint.h>

#define HDIM 4096
#define WDIM 4096
#define HWN (HDIM*WDIM)
#define NBIN 512

typedef unsigned long long u64;

// ---------------- init: zero integer binstats, init int minmax ----------------
__global__ void init_kernel(u64* __restrict__ g64, int* __restrict__ minmax) {
    int t = threadIdx.x;
    for (int i = t; i < 5 * NBIN; i += 256) g64[i] = 0ull;
    if (t < 3) { minmax[t] = 255; minmax[3 + t] = 0; }
}

// ---------------- pass A: img f32 -> lab byte planes + integer min/max ----------------
__global__ void __launch_bounds__(256) lab_kernel(const float* __restrict__ img,
                                                  uint8_t* __restrict__ lab,
                                                  int* __restrict__ minmax) {
    const int n4 = HWN / 4;
    int mn0 = 255, mn1 = 255, mn2 = 255, mx0 = 0, mx1 = 0, mx2 = 0;
    for (int i = blockIdx.x * 256 + threadIdx.x; i < n4; i += 256 * gridDim.x) {
#pragma unroll
        for (int c = 0; c < 3; c++) {
            float4 v = ((const float4*)(img + (size_t)c * HWN))[i];
            int b0 = (int)floorf(v.x * 255.f); b0 = b0 < 0 ? 0 : (b0 > 255 ? 255 : b0);
            int b1 = (int)floorf(v.y * 255.f); b1 = b1 < 0 ? 0 : (b1 > 255 ? 255 : b1);
            int b2 = (int)floorf(v.z * 255.f); b2 = b2 < 0 ? 0 : (b2 > 255 ? 255 : b2);
            int b3 = (int)floorf(v.w * 255.f); b3 = b3 < 0 ? 0 : (b3 > 255 ? 255 : b3);
            ((unsigned*)(lab + (size_t)c * HWN))[i] =
                (unsigned)b0 | ((unsigned)b1 << 8) | ((unsigned)b2 << 16) | ((unsigned)b3 << 24);
            int lmn = min(min(b0, b1), min(b2, b3));
            int lmx = max(max(b0, b1), max(b2, b3));
            if (c == 0) { mn0 = min(mn0, lmn); mx0 = max(mx0, lmx); }
            else if (c == 1) { mn1 = min(mn1, lmn); mx1 = max(mx1, lmx); }
            else { mn2 = min(mn2, lmn); mx2 = max(mx2, lmx); }
        }
    }
#pragma unroll
    for (int off = 32; off > 0; off >>= 1) {
        mn0 = min(mn0, __shfl_down(mn0, off)); mx0 = max(mx0, __shfl_down(mx0, off));
        mn1 = min(mn1, __shfl_down(mn1, off)); mx1 = max(mx1, __shfl_down(mx1, off));
        mn2 = min(mn2, __shfl_down(mn2, off)); mx2 = max(mx2, __shfl_down(mx2, off));
    }
    __shared__ int smn[3][4], smx[3][4];
    int lane = threadIdx.x & 63, wid = threadIdx.x >> 6;
    if (lane == 0) {
        smn[0][wid] = mn0; smx[0][wid] = mx0;
        smn[1][wid] = mn1; smx[1][wid] = mx1;
        smn[2][wid] = mn2; smx[2][wid] = mx2;
    }
    __syncthreads();
    if (threadIdx.x < 3) {
        int c = threadIdx.x;
        int a = min(min(smn[c][0], smn[c][1]), min(smn[c][2], smn[c][3]));
        int z = max(max(smx[c][0], smx[c][1]), max(smx[c][2], smx[c][3]));
        atomicMin(&minmax[c], a);
        atomicMax(&minmax[3 + c], z);
    }
}

// ---------------- pass B: threshold-binning quantize, no LDS reads in pixel loop ----------------
// bin via 7 integer thresholds/channel: T_k = first byte t with floor((t-cmn)/step) >= k,
// found by binary search using the SAME IEEE f32 division as the reference (bit-exact).
// LDS pipe carries ONLY fire-and-forget ds_add_u64 (2/px) -> no lgkmcnt stalls in loop.
__global__ void __launch_bounds__(256) quant_kernel(const uint8_t* __restrict__ lab,
                                                    const int* __restrict__ minmax,
                                                    uint16_t* __restrict__ linmap,
                                                    u64* __restrict__ g64) {
    __shared__ int sT[3][8];   // [channel][k], k=1..7 used
    __shared__ u64 sA[NBIN], sB[NBIN];
    for (int i = threadIdx.x; i < NBIN; i += 256) { sA[i] = 0ull; sB[i] = 0ull; }
    if (threadIdx.x < 21) {
        int c = threadIdx.x / 7, k = threadIdx.x % 7 + 1;
        float cmn = (float)minmax[c];
        float cmx = (float)minmax[3 + c];
        float step = fmaxf((cmx - cmn) / 8.f, 1e-12f);
        int lo = 0, hi = 256;
        while (lo < hi) {
            int mid = (lo + hi) >> 1;
            float q = floorf(((float)mid - cmn) / step);
            int qi = (int)q;
            qi = qi < 0 ? 0 : (qi > 7 ? 7 : qi);
            if (qi >= k) hi = mid; else lo = mid + 1;
        }
        sT[c][k] = lo;   // 256 if never reached
    }
    __syncthreads();
    int TA[8], TB[8], TC[8];
#pragma unroll
    for (int k = 1; k < 8; k++) { TA[k] = sT[0][k]; TB[k] = sT[1][k]; TC[k] = sT[2][k]; }
    const uint4* p0 = (const uint4*)lab;
    const uint4* p1 = (const uint4*)(lab + (size_t)HWN);
    const uint4* p2 = (const uint4*)(lab + (size_t)2 * HWN);
    const int n16 = HWN / 16;
    for (int i = blockIdx.x * 256 + threadIdx.x; i < n16; i += 256 * gridDim.x) {
        uint4 A = p0[i], B = p1[i], C = p2[i];
        unsigned wa[4] = {A.x, A.y, A.z, A.w};
        unsigned wb[4] = {B.x, B.y, B.z, B.w};
        unsigned wc[4] = {C.x, C.y, C.z, C.w};
        int p = i * 16;
        int y = p >> 12;
        int xb = p & (WDIM - 1);
        u64 Abase = (1ull << 52) | (u64)(unsigned)y;
        u64 Bbase = (u64)(unsigned)(y * y);
        unsigned short bins[16];
#pragma unroll
        for (int w = 0; w < 4; w++) {
#pragma unroll
            for (int k = 0; k < 4; k++) {
                int l0 = (wa[w] >> (8 * k)) & 255;
                int l1 = (wb[w] >> (8 * k)) & 255;
                int l2 = (wc[w] >> (8 * k)) & 255;
                int q0 = 0, q1 = 0, q2 = 0;
#pragma unroll
                for (int kk = 1; kk < 8; kk++) {
                    q0 += (l0 >= TA[kk]);
                    q1 += (l1 >= TB[kk]);
                    q2 += (l2 >= TC[kk]);
                }
                int bin = (q0 << 6) | (q1 << 3) | q2;
                bins[w * 4 + k] = (unsigned short)bin;
                int x = xb + w * 4 + k;
                atomicAdd(&sA[bin], Abase | ((u64)(unsigned)x << 26));
                atomicAdd(&sB[bin], ((u64)(unsigned)(x * x) << 32) | Bbase);
            }
        }
        uint4 o0, o1;
        o0.x = (unsigned)bins[0] | ((unsigned)bins[1] << 16);
        o0.y = (unsigned)bins[2] | ((unsigned)bins[3] << 16);
        o0.z = (unsigned)bins[4] | ((unsigned)bins[5] << 16);
        o0.w = (unsigned)bins[6] | ((unsigned)bins[7] << 16);
        o1.x = (unsigned)bins[8] | ((unsigned)bins[9] << 16);
        o1.y = (unsigned)bins[10] | ((unsigned)bins[11] << 16);
        o1.z = (unsigned)bins[12] | ((unsigned)bins[13] << 16);
        o1.w = (unsigned)bins[14] | ((unsigned)bins[15] << 16);
        ((uint4*)linmap)[i * 2] = o0;
        ((uint4*)linmap)[i * 2 + 1] = o1;
    }
    __syncthreads();
    for (int i = threadIdx.x; i < NBIN; i += 256) {
        u64 A = sA[i];
        if (A) {
            u64 B = sB[i];
            atomicAdd(&g64[i],            A >> 52);
            atomicAdd(&g64[NBIN + i],     (A >> 26) & 0x3FFFFFFull);
            atomicAdd(&g64[2 * NBIN + i], A & 0x3FFFFFFull);
            atomicAdd(&g64[3 * NBIN + i], B >> 32);
            atomicAdd(&g64[4 * NBIN + i], B & 0xFFFFFFFFull);
        }
    }
}

// ------- helper: compute bin-edge tables into LDS (24 threads) -------
__device__ inline void load_edges(const int* minmax, float* e0, float* e1, float* e2, int tid) {
    if (tid < 24) {
        int c = tid >> 3, k = tid & 7;
        float cmn = (float)minmax[c];
        float cmx = (float)minmax[3 + c];
        float step = fmaxf((cmx - cmn) / 8.f, 1e-12f);
        float e = cmn + (float)k * step;
        if (c == 0) e0[k] = e; else if (c == 1) e1[k] = e; else e2[k] = e;
    }
}

// ---------------- pass C1: bilateral matvecs + shape prob -> salm, maskf ----------------
__global__ void __launch_bounds__(512) binstat1_kernel(const u64* __restrict__ g64,
                                                       const int* __restrict__ minmax,
                                                       float* __restrict__ salm,
                                                       float* __restrict__ maskf) {
    __shared__ float sh[NBIN], sx[NBIN], sy[NBIN], sx2[NBIN], sy2[NBIN];
    __shared__ float e0[8], e1[8], e2[8];
    __shared__ float parts[6][8][64];
    const int tid = threadIdx.x;
    const int bl = tid & 63, jc = tid >> 6;
    if (tid < NBIN) {
        sh[tid]  = (float)g64[tid];
        sx[tid]  = (float)g64[NBIN + tid];
        sy[tid]  = (float)g64[2 * NBIN + tid];
        sx2[tid] = (float)g64[3 * NBIN + tid];
        sy2[tid] = (float)g64[4 * NBIN + tid];
    }
    load_edges(minmax, e0, e1, e2, tid);
    __syncthreads();
    const int bin = blockIdx.x * 64 + bl;
    const float c0 = e0[bin >> 6], c1 = e1[(bin >> 3) & 7], c2 = e2[bin & 7];
    float contrast = 0.f, en = 0.f, ex = 0.f, ey = 0.f, ex2 = 0.f, ey2 = 0.f;
    for (int j = jc * 64; j < jc * 64 + 64; j++) {
        float d0 = c0 - e0[j >> 6], d1 = c1 - e1[(j >> 3) & 7], d2c = c2 - e2[j & 7];
        float d2 = d0 * d0 + d1 * d1 + d2c * d2c;
        float D = sqrtf(d2);
        float E = __expf(-d2 * (1.f / 512.f));
        float h = sh[j];
        contrast += D * h; en += E * h;
        ex += E * sx[j]; ey += E * sy[j]; ex2 += E * sx2[j]; ey2 += E * sy2[j];
    }
    parts[0][jc][bl] = contrast; parts[1][jc][bl] = en;
    parts[2][jc][bl] = ex;       parts[3][jc][bl] = ey;
    parts[4][jc][bl] = ex2;      parts[5][jc][bl] = ey2;
    __syncthreads();
    if (jc == 0) {
        contrast = 0.f; en = 0.f; ex = 0.f; ey = 0.f; ex2 = 0.f; ey2 = 0.f;
        for (int w = 0; w < 8; w++) {
            contrast += parts[0][w][bl]; en  += parts[1][w][bl];
            ex       += parts[2][w][bl]; ey  += parts[3][w][bl];
            ex2      += parts[4][w][bl]; ey2 += parts[5][w][bl];
        }
        float norm = fmaxf(en, 1e-8f);
        float mx = ex / norm, my = ey / norm, mx2 = ex2 / norm, my2 = ey2 / norm;
        float vx = fmaxf(mx2 - mx * mx, 0.f), vy = fmaxf(my2 - my * my, 0.f);
        float g0 = sqrtf(12.f * vx) / 4096.f;
        float g1 = sqrtf(12.f * vy) / 4096.f;
        float g2 = (mx - 2048.f) / 4096.f;
        float g3 = (my - 2048.f) / 4096.f;
        const float CI[4][4] = {{43.3777f, 1.7633f, -0.4059f, 1.0997f},
                                {1.7633f, 40.7221f, -0.0165f, 0.0447f},
                                {-0.4059f, -0.0165f, 87.0455f, -3.2744f},
                                {1.0997f, 0.0447f, -3.2744f, 125.1503f}};
        float xc[4] = {g0 - 0.5555f, g1 - 0.6449f, g2 - 0.0002f, g3 - 0.0063f};
        float maha = 0.f;
#pragma unroll
        for (int ii = 0; ii < 4; ii++)
#pragma unroll
            for (int jj = 0; jj < 4; jj++) maha += xc[ii] * CI[ii][jj] * xc[jj];
        float sp = __expf(-0.5f * maha);
        float mf = sh[bin] > 0.f ? 1.f : 0.f;
        salm[bin] = contrast * sp * mf;
        maskf[bin] = mf;
    }
}

// ---------------- pass C2: smoothing matvec -> smoothed ----------------
__global__ void __launch_bounds__(512) binstat2_kernel(const float* __restrict__ salm,
                                                       const float* __restrict__ maskf,
                                                       const int* __restrict__ minmax,
                                                       float* __restrict__ smoothed) {
    __shared__ float ssal[NBIN], smsk[NBIN];
    __shared__ float e0[8], e1[8], e2[8];
    __shared__ float parts[2][8][64];
    const int tid = threadIdx.x;
    const int bl = tid & 63, jc = tid >> 6;
    if (tid < NBIN) { ssal[tid] = salm[tid]; smsk[tid] = maskf[tid]; }
    load_edges(minmax, e0, e1, e2, tid);
    __syncthreads();
    const int bin = blockIdx.x * 64 + bl;
    const float c0 = e0[bin >> 6], c1 = e1[(bin >> 3) & 7], c2 = e2[bin & 7];
    float num = 0.f, den = 0.f;
    for (int j = jc * 64; j < jc * 64 + 64; j++) {
        float d0 = c0 - e0[j >> 6], d1 = c1 - e1[(j >> 3) & 7], d2c = c2 - e2[j & 7];
        float d2 = d0 * d0 + d1 * d1 + d2c * d2c;
        float E = __expf(-d2 * (1.f / 512.f));
        num += E * ssal[j]; den += E * smsk[j];
    }
    parts[0][jc][bl] = num; parts[1][jc][bl] = den;
    __syncthreads();
    if (jc == 0) {
        num = 0.f; den = 0.f;
        for (int w = 0; w < 8; w++) { num += parts[0][w][bl]; den += parts[1][w][bl]; }
        smoothed[bin] = num / fmaxf(den, 1e-8f);
    }
}

// ---------------- pass C3: min/max over occupied bins -> norm_sal ----------------
__global__ void __launch_bounds__(512) norm_kernel(const float* __restrict__ smoothed,
                                                   const float* __restrict__ maskf,
                                                   float* __restrict__ norm_sal) {
    __shared__ float rmn[8], rmx[8];
    const int b = threadIdx.x;
    float sm = smoothed[b];
    float mf = maskf[b];
    float vmn = mf > 0.f ? sm : INFINITY;
    float vmx = mf > 0.f ? sm : -INFINITY;
#pragma unroll
    for (int off = 32; off > 0; off >>= 1) {
        vmn = fminf(vmn, __shfl_down(vmn, off));
        vmx = fmaxf(vmx, __shfl_down(vmx, off));
    }
    int lane = b & 63, wid = b >> 6;
    if (lane == 0) { rmn[wid] = vmn; rmx[wid] = vmx; }
    __syncthreads();
    if (b == 0) {
        float a = rmn[0], z = rmx[0];
        for (int w = 1; w < 8; w++) { a = fminf(a, rmn[w]); z = fmaxf(z, rmx[w]); }
        rmn[0] = a; rmx[0] = z;
    }
    __syncthreads();
    float mnv = rmn[0], mxv = rmx[0];
    float ns = (mxv > mnv) ? 255.f * (sm - mnv) / fmaxf(mxv - mnv, 1e-30f) : 0.f;
    norm_sal[b] = ns;
}

// ---------------- pass D: gather + horizontal 10-tap sum (fp16 temp) ----------------
#define RPB 4
__global__ void __launch_bounds__(256) hblur_kernel(const uint16_t* __restrict__ linmap,
                                                    const float* __restrict__ norm_sal,
                                                    _Float16* __restrict__ temp) {
    __shared__ float lut[NBIN];
    __shared__ float sv[256 + 9];
    for (int i = threadIdx.x; i < NBIN; i += 256) lut[i] = norm_sal[i];
    const int x0 = blockIdx.x * 256;
    for (int r = 0; r < RPB; r++) {
        const int y = blockIdx.y * RPB + r;
        __syncthreads();
        for (int t = threadIdx.x; t < 265; t += 256) {
            int v = x0 - 5 + t;
            v = v < 0 ? -v : (v >= WDIM ? 2 * WDIM - 2 - v : v);  // reflect-101
            sv[t] = lut[linmap[(size_t)y * WDIM + v]];
        }
        __syncthreads();
        float s = 0.f;
#pragma unroll
        for (int k = 0; k < 10; k++) s += sv[threadIdx.x + k];
        temp[(size_t)y * WDIM + x0 + threadIdx.x] = (_Float16)s;
    }
}

// ---------------- pass E: vertical 10-tap sliding sum + scale ----------------
#define YB 128
__global__ void __launch_bounds__(256) vblur_kernel(const _Float16* __restrict__ temp,
                                                    float* __restrict__ out) {
    const int x = blockIdx.x * 256 + threadIdx.x;
    const int y0 = blockIdx.y * YB;
    float s = 0.f;
#pragma unroll
    for (int u = y0 - 5; u < y0 + 5; u++) {
        int ur = u < 0 ? -u : (u >= HDIM ? 2 * HDIM - 2 - u : u);
        s += (float)temp[(size_t)ur * WDIM + x];
    }
    for (int yy = y0; yy < y0 + YB; yy++) {
        out[(size_t)yy * WDIM + x] = s * (1.f / 100.f) * (1.f / 255.f);
        int ua = yy + 5, ub = yy - 5;
        int ura = ua >= HDIM ? 2 * HDIM - 2 - ua : ua;
        int urb = ub < 0 ? -ub : ub;
        s += (float)temp[(size_t)ura * WDIM + x] - (float)temp[(size_t)urb * WDIM + x];
    }
}

extern "C" void kernel_launch(void* const* d_in, const int* in_sizes, int n_in,
                              void* d_out, int out_size, void* d_ws, size_t ws_size,
                              hipStream_t stream) {
    const float* img = (const float*)d_in[0];
    float* out = (float*)d_out;
    char* ws = (char*)d_ws;
    // ws: lab (3*HWN) | linmap u16 (2*HWN) | temp fp16 (2*HWN) | g64 (5*512*8) |
    //     minmax (24B pad 32) | salm | maskf | smoothed | norm_sal (512 f32 each)
    uint8_t* lab = (uint8_t*)ws;
    uint16_t* linmap = (uint16_t*)(ws + (size_t)3 * HWN);
    _Float16* temp = (_Float16*)(ws + (size_t)5 * HWN);
    u64* g64 = (u64*)(ws + (size_t)7 * HWN);
    char* tail = ws + (size_t)7 * HWN + 20480;
    int* minmax = (int*)tail;
    float* salm = (float*)(tail + 32);
    float* maskf = (float*)(tail + 32 + 2048);
    float* smoothed = (float*)(tail + 32 + 4096);
    float* norm_sal = (float*)(tail + 32 + 6144);

    init_kernel<<<1, 256, 0, stream>>>(g64, minmax);
    lab_kernel<<<2048, 256, 0, stream>>>(img, lab, minmax);
    quant_kernel<<<1024, 256, 0, stream>>>(lab, minmax, linmap, g64);
    binstat1_kernel<<<8, 512, 0, stream>>>(g64, minmax, salm, maskf);
    binstat2_kernel<<<8, 512, 0, stream>>>(salm, maskf, minmax, smoothed);
    norm_kernel<<<1, 512, 0, stream>>>(smoothed, maskf, norm_sal);
    hblur_kernel<<<dim3(WDIM / 256, HDIM / RPB), 256, 0, stream>>>(linmap, norm_sal, temp);
    vblur_kernel<<<dim3(WDIM / 256, HDIM / YB), 256, 0, stream>>>(temp, out);
}